// Round 1
// 824.763 us; speedup vs baseline: 1.1765x; 1.1765x over previous
//
#include <hip/hip_runtime.h>
#include <math.h>

// N=64, T=2048, E=512, A=256, D=512, S=64, O=80, H4=2048
// Algebraic facts exploited:
//  - att0 one-hot at t=0 -> attention window = t in [0,10); softmax max-shift cancels
//  - h=c=0 into both LSTM cells -> Whh* unused; f-gate rows of Wih* unused
//  - conv(one-hot) = conv_w[a, 15-t]
//
// ws layout (floats):
//   XT0 @ 0       : 1088*64  in_lstm^T (k-major: rows 0..512 prenet p | 512..1024 ctx | 1024..1088 spkr)
//   G   @ 69632   : 6144*64  gates^T compact (i | g | o), reused both layers
//                   -> after last lstm_act reads it, first 204800 floats reused as PART
//   XT1 @ 462848  : 2048*64  h1^T then h2^T
//   HID @ 593920  : 64*1024  prenet hidden, n-major
//   SP  @ 659456  : 64*512   sp, n-major

__device__ __forceinline__ float sigmoidf_(float x){ return 1.0f/(1.0f+expf(-x)); }
__device__ __forceinline__ float softsignf_(float x){ return x/(1.0f+fabsf(x)); }

// ---- Pattern A small GEMMs: block = one n (x loads scalar-uniform), threads = j (W coalesced)

// hidden[n,j] = relu(concat(input_dec,spkr)[n,:] @ pre_W1 + pre_b1), J=1024, K=144
__global__ void hidden_kernel(const float* __restrict__ input_dec, const float* __restrict__ spkr,
                              const float* __restrict__ W, const float* __restrict__ b,
                              float* __restrict__ hid)
{
    const int n = blockIdx.x;
    const int j = blockIdx.y * 256 + threadIdx.x;   // < 1024
    float a0=0.f, a1=0.f, a2=0.f, a3=0.f;
    #pragma unroll 4
    for (int k = 0; k < 144; k += 4) {
        const float x0 = (k+0 < 80) ? input_dec[n*80 + k+0] : spkr[n*64 + (k+0-80)];
        const float x1 = (k+1 < 80) ? input_dec[n*80 + k+1] : spkr[n*64 + (k+1-80)];
        const float x2 = (k+2 < 80) ? input_dec[n*80 + k+2] : spkr[n*64 + (k+2-80)];
        const float x3 = (k+3 < 80) ? input_dec[n*80 + k+3] : spkr[n*64 + (k+3-80)];
        a0 = fmaf(x0, W[(k+0)*1024 + j], a0);
        a1 = fmaf(x1, W[(k+1)*1024 + j], a1);
        a2 = fmaf(x2, W[(k+2)*1024 + j], a2);
        a3 = fmaf(x3, W[(k+3)*1024 + j], a3);
    }
    hid[n*1024 + j] = fmaxf((a0+a1)+(a2+a3) + b[j], 0.f);
}

// sp[n,j] = tanh(relu(speed*sp_W1+sp_b1) @ sp_W2 + sp_b2), J=512, K=512
__global__ void sp_kernel(const float* __restrict__ speed, const float* __restrict__ sp_W1,
                          const float* __restrict__ sp_b1, const float* __restrict__ sp_W2,
                          const float* __restrict__ sp_b2, float* __restrict__ sp)
{
    const int n = blockIdx.x;
    const int j = blockIdx.y * 256 + threadIdx.x;   // < 512
    const float s = speed[n];
    float a0=0.f, a1=0.f, a2=0.f, a3=0.f;
    #pragma unroll 4
    for (int d = 0; d < 512; d += 4) {
        const float r0 = fmaxf(fmaf(s, sp_W1[d+0], sp_b1[d+0]), 0.f);
        const float r1 = fmaxf(fmaf(s, sp_W1[d+1], sp_b1[d+1]), 0.f);
        const float r2 = fmaxf(fmaf(s, sp_W1[d+2], sp_b1[d+2]), 0.f);
        const float r3 = fmaxf(fmaf(s, sp_W1[d+3], sp_b1[d+3]), 0.f);
        a0 = fmaf(r0, sp_W2[(d+0)*512 + j], a0);
        a1 = fmaf(r1, sp_W2[(d+1)*512 + j], a1);
        a2 = fmaf(r2, sp_W2[(d+2)*512 + j], a2);
        a3 = fmaf(r3, sp_W2[(d+3)*512 + j], a3);
    }
    sp[n*512 + j] = tanhf((a0+a1)+(a2+a3) + sp_b2[j]);
}

// p[n,j] = relu(hid[n,:] @ pre_W2 + pre_b2) -> XT0 rows [0,512), J=512, K=1024
__global__ void p_kernel(const float* __restrict__ hid, const float* __restrict__ W,
                         const float* __restrict__ b, float* __restrict__ xT0)
{
    const int n = blockIdx.x;
    const int j = blockIdx.y * 256 + threadIdx.x;   // < 512
    const float* xr = hid + n*1024;
    float a0=0.f, a1=0.f, a2=0.f, a3=0.f;
    #pragma unroll 4
    for (int k = 0; k < 1024; k += 4) {
        a0 = fmaf(xr[k+0], W[(k+0)*512 + j], a0);
        a1 = fmaf(xr[k+1], W[(k+1)*512 + j], a1);
        a2 = fmaf(xr[k+2], W[(k+2)*512 + j], a2);
        a3 = fmaf(xr[k+3], W[(k+3)*512 + j], a3);
    }
    xT0[j*64 + n] = fmaxf((a0+a1)+(a2+a3) + b[j], 0.f);
}

// attention + context, one block per batch row n, 256 threads (= a index)
__global__ void attn_kernel(const float* __restrict__ input_enc,
                            const float* __restrict__ spkr,
                            const float* __restrict__ speed,
                            const int*   __restrict__ lengths,
                            const float* __restrict__ We,
                            const float* __restrict__ be,
                            const float* __restrict__ Ws,
                            const float* __restrict__ conv_w,
                            const float* __restrict__ w_proj,
                            const float* __restrict__ b_proj,
                            const float* __restrict__ W_speed,
                            const float* __restrict__ sp,
                            float* __restrict__ xT0,
                            float* __restrict__ out_ctx,
                            float* __restrict__ out_dec)
{
    const int n = blockIdx.x;
    const int a = threadIdx.x;               // 256 threads
    __shared__ float encs[10*512];           // 20 KB
    __shared__ float part[4][10];
    __shared__ float logit_s[10];
    __shared__ float att_s[10];

    const int L1 = lengths[n] - 1;
    const int tc = (L1 + 1 < 10) ? (L1 + 1) : 10;
    const float sn = speed[n];
    const float* enc_n = input_enc + (size_t)n * (2048*512);

    for (int idx = a; idx < 10*512; idx += 256) encs[idx] = enc_n[idx];
    __syncthreads();

    float ds = 0.f;
    for (int s = 0; s < 64; ++s) ds = fmaf(spkr[n*64 + s], Ws[s*256 + a], ds);
    const float bspkr = softsignf_(ds);
    const float bspd  = sn * W_speed[a];
    const float bea   = be[a];
    const float wpa   = w_proj[a];

    float dt[10];
    #pragma unroll
    for (int t = 0; t < 10; ++t) dt[t] = 0.f;
    for (int k = 0; k < 512; ++k) {
        const float w = We[k*256 + a];
        #pragma unroll
        for (int t = 0; t < 10; ++t) dt[t] = fmaf(encs[t*512 + k], w, dt[t]);
    }

    for (int t = 0; t < 10; ++t) {
        float e = softsignf_(dt[t] + bea);
        e += bspkr + conv_w[a*31 + (15 - t)] + bspd;
        float v = tanhf(e) * wpa;
        #pragma unroll
        for (int off = 32; off > 0; off >>= 1) v += __shfl_down(v, off);
        if ((a & 63) == 0) part[a >> 6][t] = v;
    }
    __syncthreads();
    if (a < 10) logit_s[a] = part[0][a] + part[1][a] + part[2][a] + part[3][a] + b_proj[0];
    __syncthreads();
    if (a == 0) {
        float mx = -1e30f;
        for (int t = 0; t < tc; ++t) mx = fmaxf(mx, logit_s[t]);
        float ssum = 0.f;
        for (int t = 0; t < tc; ++t) { att_s[t] = expf(logit_s[t] - mx); ssum += att_s[t]; }
        const float inv = 1.f / fmaxf(ssum, 1e-12f);
        for (int t = 0; t < tc; ++t) att_s[t] *= inv;
        for (int t = tc; t < 10; ++t) att_s[t] = 0.f;
    }
    __syncthreads();

    for (int e0 = a; e0 < 512; e0 += 256) {
        const float spv = sp[n*512 + e0];
        float c = 0.f;
        for (int t = 0; t < tc; ++t) c = fmaf(att_s[t], encs[t*512 + e0] + spv, c);
        xT0[(512 + e0)*64 + n] = c;
        out_ctx[n*512 + e0]   = c;
        out_dec[n*2560 + 2048 + e0] = c;
    }
    if (a < 64) xT0[(1024 + a)*64 + n] = spkr[n*64 + a];
}

// big skinny GEMM: lanes = n, 2 waves/block, 4 rows/thread -> 8 rows/block, 768 blocks
template<int K, bool FSKIP>
__global__ void gemm_big(const float* __restrict__ xT, const float* __restrict__ W,
                         const float* __restrict__ b1, const float* __restrict__ b2,
                         float* __restrict__ outT)
{
    const int tid = threadIdx.x;              // 128 threads
    const int n = tid & 63;
    const int wv = __builtin_amdgcn_readfirstlane(tid >> 6);
    const int jj0 = blockIdx.x * 8 + wv * 4;
    const int j0  = (FSKIP && jj0 >= 2048) ? jj0 + 2048 : jj0;
    const float* Wr = W + (size_t)j0 * K;
    float acc0 = 0.f, acc1 = 0.f, acc2 = 0.f, acc3 = 0.f;
    #pragma unroll 2
    for (int k = 0; k < K; k += 4) {
        const float x0 = xT[(k+0)*64 + n];
        const float x1 = xT[(k+1)*64 + n];
        const float x2 = xT[(k+2)*64 + n];
        const float x3 = xT[(k+3)*64 + n];
        const float4 w0 = *reinterpret_cast<const float4*>(Wr + (size_t)0*K + k);
        const float4 w1 = *reinterpret_cast<const float4*>(Wr + (size_t)1*K + k);
        const float4 w2 = *reinterpret_cast<const float4*>(Wr + (size_t)2*K + k);
        const float4 w3 = *reinterpret_cast<const float4*>(Wr + (size_t)3*K + k);
        acc0 = fmaf(x3, w0.w, fmaf(x2, w0.z, fmaf(x1, w0.y, fmaf(x0, w0.x, acc0))));
        acc1 = fmaf(x3, w1.w, fmaf(x2, w1.z, fmaf(x1, w1.y, fmaf(x0, w1.x, acc1))));
        acc2 = fmaf(x3, w2.w, fmaf(x2, w2.z, fmaf(x1, w2.y, fmaf(x0, w2.x, acc2))));
        acc3 = fmaf(x3, w3.w, fmaf(x2, w3.z, fmaf(x1, w3.y, fmaf(x0, w3.x, acc3))));
    }
    acc0 += b1[j0+0] + b2[j0+0];
    acc1 += b1[j0+1] + b2[j0+1];
    acc2 += b1[j0+2] + b2[j0+2];
    acc3 += b1[j0+3] + b2[j0+3];
    outT[(jj0+0)*64 + n] = acc0;
    outT[(jj0+1)*64 + n] = acc1;
    outT[(jj0+2)*64 + n] = acc2;
    outT[(jj0+3)*64 + n] = acc3;
}

// h = sigmoid(o)*tanh(sigmoid(i)*tanh(g)); gates compact rows i|g|o
__global__ void lstm_act_kernel(const float* __restrict__ gT, float* __restrict__ hT,
                                float* __restrict__ dec_out)
{
    const int idx = blockIdx.x * 256 + threadIdx.x;   // 64*2048
    const int n = idx & 63;
    const int m = idx >> 6;
    const float gi = gT[idx];
    const float gg = gT[2048*64 + idx];
    const float go = gT[4096*64 + idx];
    const float c = sigmoidf_(gi) * tanhf(gg);
    const float h = sigmoidf_(go) * tanhf(c);
    hT[idx] = h;
    if (dec_out) dec_out[n*2560 + m] = h;
}

// final GEMM, K-split: out[n,j] = dec_output[n,:] @ Wo + bo
// K=2560 split into 20 chunks of 128; chunks 0..15 read h2T (k-major), 16..19 read ctx (n-major).
// grid (64 n, 20 kc), 256 threads (160 active = j, coalesced on Wo). Partials -> PART (aliases G).
__global__ void final_partial_kernel(const float* __restrict__ h2T, const float* __restrict__ ctx,
                                     const float* __restrict__ Wo, float* __restrict__ part)
{
    const int n  = blockIdx.x;
    const int kc = blockIdx.y;
    const int j  = threadIdx.x;               // 160 active
    if (j >= 160) return;
    const int k0 = kc * 128;
    float a0=0.f, a1=0.f, a2=0.f, a3=0.f;
    if (kc < 16) {
        #pragma unroll 4
        for (int k = k0; k < k0 + 128; k += 4) {
            a0 = fmaf(h2T[(k+0)*64 + n], Wo[(k+0)*160 + j], a0);
            a1 = fmaf(h2T[(k+1)*64 + n], Wo[(k+1)*160 + j], a1);
            a2 = fmaf(h2T[(k+2)*64 + n], Wo[(k+2)*160 + j], a2);
            a3 = fmaf(h2T[(k+3)*64 + n], Wo[(k+3)*160 + j], a3);
        }
    } else {
        const float* cr = ctx + n*512;
        #pragma unroll 4
        for (int k = k0; k < k0 + 128; k += 4) {
            a0 = fmaf(cr[k+0-2048], Wo[(k+0)*160 + j], a0);
            a1 = fmaf(cr[k+1-2048], Wo[(k+1)*160 + j], a1);
            a2 = fmaf(cr[k+2-2048], Wo[(k+2)*160 + j], a2);
            a3 = fmaf(cr[k+3-2048], Wo[(k+3)*160 + j], a3);
        }
    }
    part[(kc*64 + n)*160 + j] = (a0+a1)+(a2+a3);
}

__global__ void final_reduce_kernel(const float* __restrict__ part, const float* __restrict__ bo,
                                    float* __restrict__ out)
{
    const int idx = blockIdx.x * 256 + threadIdx.x;   // < 10240 = 64*160
    const int j = idx - (idx / 160) * 160;
    float s = bo[j];
    #pragma unroll
    for (int kc = 0; kc < 20; ++kc) s += part[kc*10240 + idx];
    out[idx] = s;
}

extern "C" void kernel_launch(void* const* d_in, const int* in_sizes, int n_in,
                              void* d_out, int out_size, void* d_ws, size_t ws_size,
                              hipStream_t stream)
{
    const float* input_enc = (const float*)d_in[0];
    const float* input_dec = (const float*)d_in[1];
    const float* spkr      = (const float*)d_in[2];
    const float* speed     = (const float*)d_in[3];
    const int*   lengths   = (const int*)  d_in[4];
    const float* We        = (const float*)d_in[5];
    const float* be        = (const float*)d_in[6];
    const float* Ws        = (const float*)d_in[7];
    const float* conv_w    = (const float*)d_in[8];
    const float* w_proj    = (const float*)d_in[9];
    const float* b_proj    = (const float*)d_in[10];
    const float* W_speed   = (const float*)d_in[11];
    const float* sp_W1     = (const float*)d_in[12];
    const float* sp_b1     = (const float*)d_in[13];
    const float* sp_W2     = (const float*)d_in[14];
    const float* sp_b2     = (const float*)d_in[15];
    const float* pre_W1    = (const float*)d_in[16];
    const float* pre_b1    = (const float*)d_in[17];
    const float* pre_W2    = (const float*)d_in[18];
    const float* pre_b2    = (const float*)d_in[19];
    const float* Wih0      = (const float*)d_in[20];
    const float* bih0      = (const float*)d_in[22];
    const float* bhh0      = (const float*)d_in[23];
    const float* Wih1      = (const float*)d_in[24];
    const float* bih1      = (const float*)d_in[26];
    const float* bhh1      = (const float*)d_in[27];
    const float* Wo        = (const float*)d_in[28];
    const float* bo        = (const float*)d_in[29];

    float* ws  = (float*)d_ws;
    float* XT0 = ws;                  // 1088*64
    float* G   = ws + 69632;          // 6144*64
    float* XT1 = ws + 462848;         // 2048*64
    float* HID = ws + 593920;         // 64*1024 (n-major)
    float* SP  = ws + 659456;         // 64*512  (n-major)
    float* PART= ws + 69632;          // 20*64*160, aliases G (dead after last lstm_act)

    float* out     = (float*)d_out;   // 64*2*80
    float* out_ctx = out + 10240;     // 64*512
    float* out_dec = out + 43008;     // 64*2560

    hidden_kernel<<<dim3(64,4), 256, 0, stream>>>(input_dec, spkr, pre_W1, pre_b1, HID);
    sp_kernel<<<dim3(64,2), 256, 0, stream>>>(speed, sp_W1, sp_b1, sp_W2, sp_b2, SP);
    p_kernel<<<dim3(64,2), 256, 0, stream>>>(HID, pre_W2, pre_b2, XT0);
    attn_kernel<<<64, 256, 0, stream>>>(input_enc, spkr, speed, lengths, We, be, Ws, conv_w,
                                        w_proj, b_proj, W_speed, SP, XT0, out_ctx, out_dec);
    gemm_big<1088, true><<<768, 128, 0, stream>>>(XT0, Wih0, bih0, bhh0, G);
    lstm_act_kernel<<<512, 256, 0, stream>>>(G, XT1, nullptr);
    gemm_big<2048, true><<<768, 128, 0, stream>>>(XT1, Wih1, bih1, bhh1, G);
    lstm_act_kernel<<<512, 256, 0, stream>>>(G, XT1, out_dec);
    final_partial_kernel<<<dim3(64,20), 256, 0, stream>>>(XT1, out_ctx, Wo, PART);
    final_reduce_kernel<<<40, 256, 0, stream>>>(PART, bo, out);
}

// Round 2
// 668.593 us; speedup vs baseline: 1.4513x; 1.2336x over previous
//
#include <hip/hip_runtime.h>
#include <math.h>

// N=64, T=2048, E=512, A=256, D=512, S=64, O=80, H4=2048
// Algebraic facts exploited:
//  - att0 one-hot at t=0 -> attention window = t in [0,10); softmax max-shift cancels
//  - h=c=0 into both LSTM cells -> Whh* unused; f-gate rows of Wih* unused
//  - conv(one-hot) = conv_w[a, 15-t]
//
// ws layout (floats):
//   XT0  @ 0       : 1088*64   in_lstm^T (k-major: rows 0..512 prenet p | 512..1024 ctx | 1024..1088 spkr)
//   PART @ 69632   : 4*6144*64 gemm K-split partials (i|g|o compact), reused both layers
//                    -> dead after last lstm_act; first 204800 floats reused as FPART
//   XT1  @ 1642496 : 2048*64   h1^T then h2^T
//   HID  @ 1773568 : 64*1024   prenet hidden, n-major
//   SP   @ 1839104 : 64*512    sp, n-major

__device__ __forceinline__ float sigmoidf_(float x){ return 1.0f/(1.0f+expf(-x)); }
__device__ __forceinline__ float softsignf_(float x){ return x/(1.0f+fabsf(x)); }

// async global->LDS, 16B per lane (dest = wave-uniform base + lane*16)
__device__ __forceinline__ void llds16(const float* g, float* l)
{
    __builtin_amdgcn_global_load_lds(
        (const __attribute__((address_space(1))) unsigned int*)g,
        (__attribute__((address_space(3))) unsigned int*)l, 16, 0, 0);
}

// ---- Pattern A small GEMMs: block = one n (x loads scalar-uniform), threads = j (W coalesced)

// hidden[n,j] = relu(concat(input_dec,spkr)[n,:] @ pre_W1 + pre_b1), J=1024, K=144
__global__ void hidden_kernel(const float* __restrict__ input_dec, const float* __restrict__ spkr,
                              const float* __restrict__ W, const float* __restrict__ b,
                              float* __restrict__ hid)
{
    const int n = blockIdx.x;
    const int j = blockIdx.y * 256 + threadIdx.x;   // < 1024
    float a0=0.f, a1=0.f, a2=0.f, a3=0.f;
    #pragma unroll 4
    for (int k = 0; k < 144; k += 4) {
        const float x0 = (k+0 < 80) ? input_dec[n*80 + k+0] : spkr[n*64 + (k+0-80)];
        const float x1 = (k+1 < 80) ? input_dec[n*80 + k+1] : spkr[n*64 + (k+1-80)];
        const float x2 = (k+2 < 80) ? input_dec[n*80 + k+2] : spkr[n*64 + (k+2-80)];
        const float x3 = (k+3 < 80) ? input_dec[n*80 + k+3] : spkr[n*64 + (k+3-80)];
        a0 = fmaf(x0, W[(k+0)*1024 + j], a0);
        a1 = fmaf(x1, W[(k+1)*1024 + j], a1);
        a2 = fmaf(x2, W[(k+2)*1024 + j], a2);
        a3 = fmaf(x3, W[(k+3)*1024 + j], a3);
    }
    hid[n*1024 + j] = fmaxf((a0+a1)+(a2+a3) + b[j], 0.f);
}

// sp[n,j] = tanh(relu(speed*sp_W1+sp_b1) @ sp_W2 + sp_b2), J=512, K=512
__global__ void sp_kernel(const float* __restrict__ speed, const float* __restrict__ sp_W1,
                          const float* __restrict__ sp_b1, const float* __restrict__ sp_W2,
                          const float* __restrict__ sp_b2, float* __restrict__ sp)
{
    const int n = blockIdx.x;
    const int j = blockIdx.y * 256 + threadIdx.x;   // < 512
    const float s = speed[n];
    float a0=0.f, a1=0.f, a2=0.f, a3=0.f;
    #pragma unroll 4
    for (int d = 0; d < 512; d += 4) {
        const float r0 = fmaxf(fmaf(s, sp_W1[d+0], sp_b1[d+0]), 0.f);
        const float r1 = fmaxf(fmaf(s, sp_W1[d+1], sp_b1[d+1]), 0.f);
        const float r2 = fmaxf(fmaf(s, sp_W1[d+2], sp_b1[d+2]), 0.f);
        const float r3 = fmaxf(fmaf(s, sp_W1[d+3], sp_b1[d+3]), 0.f);
        a0 = fmaf(r0, sp_W2[(d+0)*512 + j], a0);
        a1 = fmaf(r1, sp_W2[(d+1)*512 + j], a1);
        a2 = fmaf(r2, sp_W2[(d+2)*512 + j], a2);
        a3 = fmaf(r3, sp_W2[(d+3)*512 + j], a3);
    }
    sp[n*512 + j] = tanhf((a0+a1)+(a2+a3) + sp_b2[j]);
}

// p[n,j] = relu(hid[n,:] @ pre_W2 + pre_b2) -> XT0 rows [0,512), J=512, K=1024
__global__ void p_kernel(const float* __restrict__ hid, const float* __restrict__ W,
                         const float* __restrict__ b, float* __restrict__ xT0)
{
    const int n = blockIdx.x;
    const int j = blockIdx.y * 256 + threadIdx.x;   // < 512
    const float* xr = hid + n*1024;
    float a0=0.f, a1=0.f, a2=0.f, a3=0.f;
    #pragma unroll 4
    for (int k = 0; k < 1024; k += 4) {
        a0 = fmaf(xr[k+0], W[(k+0)*512 + j], a0);
        a1 = fmaf(xr[k+1], W[(k+1)*512 + j], a1);
        a2 = fmaf(xr[k+2], W[(k+2)*512 + j], a2);
        a3 = fmaf(xr[k+3], W[(k+3)*512 + j], a3);
    }
    xT0[j*64 + n] = fmaxf((a0+a1)+(a2+a3) + b[j], 0.f);
}

// attention + context, one block per batch row n, 256 threads (= a index)
__global__ void attn_kernel(const float* __restrict__ input_enc,
                            const float* __restrict__ spkr,
                            const float* __restrict__ speed,
                            const int*   __restrict__ lengths,
                            const float* __restrict__ We,
                            const float* __restrict__ be,
                            const float* __restrict__ Ws,
                            const float* __restrict__ conv_w,
                            const float* __restrict__ w_proj,
                            const float* __restrict__ b_proj,
                            const float* __restrict__ W_speed,
                            const float* __restrict__ sp,
                            float* __restrict__ xT0,
                            float* __restrict__ out_ctx,
                            float* __restrict__ out_dec)
{
    const int n = blockIdx.x;
    const int a = threadIdx.x;               // 256 threads
    __shared__ float encs[10*512];           // 20 KB
    __shared__ float part[4][10];
    __shared__ float logit_s[10];
    __shared__ float att_s[10];

    const int L1 = lengths[n] - 1;
    const int tc = (L1 + 1 < 10) ? (L1 + 1) : 10;
    const float sn = speed[n];
    const float* enc_n = input_enc + (size_t)n * (2048*512);

    for (int idx = a; idx < 10*512; idx += 256) encs[idx] = enc_n[idx];
    __syncthreads();

    float ds = 0.f;
    for (int s = 0; s < 64; ++s) ds = fmaf(spkr[n*64 + s], Ws[s*256 + a], ds);
    const float bspkr = softsignf_(ds);
    const float bspd  = sn * W_speed[a];
    const float bea   = be[a];
    const float wpa   = w_proj[a];

    float dt[10];
    #pragma unroll
    for (int t = 0; t < 10; ++t) dt[t] = 0.f;
    for (int k = 0; k < 512; ++k) {
        const float w = We[k*256 + a];
        #pragma unroll
        for (int t = 0; t < 10; ++t) dt[t] = fmaf(encs[t*512 + k], w, dt[t]);
    }

    for (int t = 0; t < 10; ++t) {
        float e = softsignf_(dt[t] + bea);
        e += bspkr + conv_w[a*31 + (15 - t)] + bspd;
        float v = tanhf(e) * wpa;
        #pragma unroll
        for (int off = 32; off > 0; off >>= 1) v += __shfl_down(v, off);
        if ((a & 63) == 0) part[a >> 6][t] = v;
    }
    __syncthreads();
    if (a < 10) logit_s[a] = part[0][a] + part[1][a] + part[2][a] + part[3][a] + b_proj[0];
    __syncthreads();
    if (a == 0) {
        float mx = -1e30f;
        for (int t = 0; t < tc; ++t) mx = fmaxf(mx, logit_s[t]);
        float ssum = 0.f;
        for (int t = 0; t < tc; ++t) { att_s[t] = expf(logit_s[t] - mx); ssum += att_s[t]; }
        const float inv = 1.f / fmaxf(ssum, 1e-12f);
        for (int t = 0; t < tc; ++t) att_s[t] *= inv;
        for (int t = tc; t < 10; ++t) att_s[t] = 0.f;
    }
    __syncthreads();

    for (int e0 = a; e0 < 512; e0 += 256) {
        const float spv = sp[n*512 + e0];
        float c = 0.f;
        for (int t = 0; t < tc; ++t) c = fmaf(att_s[t], encs[t*512 + e0] + spv, c);
        xT0[(512 + e0)*64 + n] = c;
        out_ctx[n*512 + e0]   = c;
        out_dec[n*2560 + 2048 + e0] = c;
    }
    if (a < 64) xT0[(1024 + a)*64 + n] = spkr[n*64 + a];
}

// ---- LDS-tiled LSTM GEMM: out_part[sy][jj][n] = sum_{k in seg} W[j0][k]*xT[k][n]
// 64 j-rows x 64 n per block; K split 4-ways over blockIdx.y; 256 thr, 4j x 4n regs/thread.
// W/x tiles staged via global_load_lds width-16, double-buffered, 1 barrier per k-tile.
#define FMA_ROW(acc, wv) do { \
    acc.x = fmaf(wv.x, xk0.x, acc.x); acc.y = fmaf(wv.x, xk0.y, acc.y); \
    acc.z = fmaf(wv.x, xk0.z, acc.z); acc.w = fmaf(wv.x, xk0.w, acc.w); \
    acc.x = fmaf(wv.y, xk1.x, acc.x); acc.y = fmaf(wv.y, xk1.y, acc.y); \
    acc.z = fmaf(wv.y, xk1.z, acc.z); acc.w = fmaf(wv.y, xk1.w, acc.w); \
    acc.x = fmaf(wv.z, xk2.x, acc.x); acc.y = fmaf(wv.z, xk2.y, acc.y); \
    acc.z = fmaf(wv.z, xk2.z, acc.z); acc.w = fmaf(wv.z, xk2.w, acc.w); \
    acc.x = fmaf(wv.w, xk3.x, acc.x); acc.y = fmaf(wv.w, xk3.y, acc.y); \
    acc.z = fmaf(wv.w, xk3.z, acc.z); acc.w = fmaf(wv.w, xk3.w, acc.w); \
} while(0)

template<int K>
__global__ __launch_bounds__(256, 2)
void gemm_tile(const float* __restrict__ xT, const float* __restrict__ W,
               float* __restrict__ part)
{
    __shared__ __align__(16) float Wl[2][64*64];   // 32 KB
    __shared__ __align__(16) float Xl[2][64*64];   // 32 KB
    const int tid  = threadIdx.x;
    const int lane = tid & 63;
    const int w    = tid >> 6;            // wave 0..3
    const int tx   = tid & 15;            // n-group
    const int ty   = tid >> 4;            // j-group
    const int jjbase = blockIdx.x * 64;   // compact row base (never crosses a gate boundary)
    const int sy     = blockIdx.y;        // K segment 0..3
    const int jg     = jjbase + ((jjbase >= 2048) ? 2048 : 0);  // skip f-gate rows

    constexpr int NT = K / 64;
    constexpr int NTQ = NT / 4, NTR = NT % 4;
    const int tn = NTQ + (sy < NTR ? 1 : 0);
    const int t0 = sy * NTQ + (sy < NTR ? sy : NTR);

    float4 a0 = {0,0,0,0}, a1 = {0,0,0,0}, a2 = {0,0,0,0}, a3 = {0,0,0,0};

    // stage k-tile t into buffer b: 4 calls/wave for X (16KB contiguous), 4 for W (4 rows each)
    auto stage = [&](int t, int b) {
        const int k0 = t * 64;
        #pragma unroll
        for (int c = 0; c < 4; ++c) {
            const int u = w * 4 + c;                       // 0..15
            llds16(xT + (size_t)k0 * 64 + u * 256 + lane * 4, &Xl[b][u * 256]);
            const int r0 = u * 4;
            llds16(W + (size_t)(jg + r0 + (lane >> 4)) * K + k0 + (lane & 15) * 4,
                   &Wl[b][r0 * 64]);
        }
    };

    stage(t0, 0);
    __syncthreads();                       // drains vmcnt before barrier (HIP semantics)

    for (int tt = 0; tt < tn; ++tt) {
        const int cur = tt & 1;
        if (tt + 1 < tn) stage(t0 + tt + 1, cur ^ 1);
        const float* Wc = Wl[cur];
        const float* Xc = Xl[cur];
        #pragma unroll
        for (int kk = 0; kk < 64; kk += 4) {
            const float4 xk0 = *(const float4*)(Xc + (kk+0)*64 + tx*4);
            const float4 xk1 = *(const float4*)(Xc + (kk+1)*64 + tx*4);
            const float4 xk2 = *(const float4*)(Xc + (kk+2)*64 + tx*4);
            const float4 xk3 = *(const float4*)(Xc + (kk+3)*64 + tx*4);
            const float4 w0 = *(const float4*)(Wc + (ty*4+0)*64 + kk);
            FMA_ROW(a0, w0);
            const float4 w1 = *(const float4*)(Wc + (ty*4+1)*64 + kk);
            FMA_ROW(a1, w1);
            const float4 w2 = *(const float4*)(Wc + (ty*4+2)*64 + kk);
            FMA_ROW(a2, w2);
            const float4 w3 = *(const float4*)(Wc + (ty*4+3)*64 + kk);
            FMA_ROW(a3, w3);
        }
        __syncthreads();                   // next-tile stages complete; cur buffer free
    }

    float* op = part + (size_t)(sy * 6144 + jjbase) * 64;
    *(float4*)(op + (ty*4+0)*64 + tx*4) = a0;
    *(float4*)(op + (ty*4+1)*64 + tx*4) = a1;
    *(float4*)(op + (ty*4+2)*64 + tx*4) = a2;
    *(float4*)(op + (ty*4+3)*64 + tx*4) = a3;
}

// h = sigmoid(o)*tanh(sigmoid(i)*tanh(g)); fuses the 4-way K-split reduce + biases.
// Compact gate rows: i=m, g=2048+m, o=4096+m; global bias rows: i=m, g=4096+m, o=6144+m.
__global__ void lstm_act_kernel(const float* __restrict__ part,
                                const float* __restrict__ b1, const float* __restrict__ b2,
                                float* __restrict__ hT, float* __restrict__ dec_out)
{
    const int idx = blockIdx.x * 256 + threadIdx.x;   // 64*2048
    const int n = idx & 63;
    const int m = idx >> 6;
    float gi = b1[m]        + b2[m];
    float gg = b1[4096 + m] + b2[4096 + m];
    float go = b1[6144 + m] + b2[6144 + m];
    #pragma unroll
    for (int s = 0; s < 4; ++s) {
        gi += part[(size_t)(s * 6144 +        m) * 64 + n];
        gg += part[(size_t)(s * 6144 + 2048 + m) * 64 + n];
        go += part[(size_t)(s * 6144 + 4096 + m) * 64 + n];
    }
    const float c = sigmoidf_(gi) * tanhf(gg);
    const float h = sigmoidf_(go) * tanhf(c);
    hT[idx] = h;
    if (dec_out) dec_out[n*2560 + m] = h;
}

// final GEMM, K-split: out[n,j] = dec_output[n,:] @ Wo + bo
__global__ void final_partial_kernel(const float* __restrict__ h2T, const float* __restrict__ ctx,
                                     const float* __restrict__ Wo, float* __restrict__ part)
{
    const int n  = blockIdx.x;
    const int kc = blockIdx.y;
    const int j  = threadIdx.x;               // 160 active
    if (j >= 160) return;
    const int k0 = kc * 128;
    float a0=0.f, a1=0.f, a2=0.f, a3=0.f;
    if (kc < 16) {
        #pragma unroll 4
        for (int k = k0; k < k0 + 128; k += 4) {
            a0 = fmaf(h2T[(k+0)*64 + n], Wo[(k+0)*160 + j], a0);
            a1 = fmaf(h2T[(k+1)*64 + n], Wo[(k+1)*160 + j], a1);
            a2 = fmaf(h2T[(k+2)*64 + n], Wo[(k+2)*160 + j], a2);
            a3 = fmaf(h2T[(k+3)*64 + n], Wo[(k+3)*160 + j], a3);
        }
    } else {
        const float* cr = ctx + n*512;
        #pragma unroll 4
        for (int k = k0; k < k0 + 128; k += 4) {
            a0 = fmaf(cr[k+0-2048], Wo[(k+0)*160 + j], a0);
            a1 = fmaf(cr[k+1-2048], Wo[(k+1)*160 + j], a1);
            a2 = fmaf(cr[k+2-2048], Wo[(k+2)*160 + j], a2);
            a3 = fmaf(cr[k+3-2048], Wo[(k+3)*160 + j], a3);
        }
    }
    part[(kc*64 + n)*160 + j] = (a0+a1)+(a2+a3);
}

__global__ void final_reduce_kernel(const float* __restrict__ part, const float* __restrict__ bo,
                                    float* __restrict__ out)
{
    const int idx = blockIdx.x * 256 + threadIdx.x;   // < 10240 = 64*160
    const int j = idx - (idx / 160) * 160;
    float s = bo[j];
    #pragma unroll
    for (int kc = 0; kc < 20; ++kc) s += part[kc*10240 + idx];
    out[idx] = s;
}

extern "C" void kernel_launch(void* const* d_in, const int* in_sizes, int n_in,
                              void* d_out, int out_size, void* d_ws, size_t ws_size,
                              hipStream_t stream)
{
    const float* input_enc = (const float*)d_in[0];
    const float* input_dec = (const float*)d_in[1];
    const float* spkr      = (const float*)d_in[2];
    const float* speed     = (const float*)d_in[3];
    const int*   lengths   = (const int*)  d_in[4];
    const float* We        = (const float*)d_in[5];
    const float* be        = (const float*)d_in[6];
    const float* Ws        = (const float*)d_in[7];
    const float* conv_w    = (const float*)d_in[8];
    const float* w_proj    = (const float*)d_in[9];
    const float* b_proj    = (const float*)d_in[10];
    const float* W_speed   = (const float*)d_in[11];
    const float* sp_W1     = (const float*)d_in[12];
    const float* sp_b1     = (const float*)d_in[13];
    const float* sp_W2     = (const float*)d_in[14];
    const float* sp_b2     = (const float*)d_in[15];
    const float* pre_W1    = (const float*)d_in[16];
    const float* pre_b1    = (const float*)d_in[17];
    const float* pre_W2    = (const float*)d_in[18];
    const float* pre_b2    = (const float*)d_in[19];
    const float* Wih0      = (const float*)d_in[20];
    const float* bih0      = (const float*)d_in[22];
    const float* bhh0      = (const float*)d_in[23];
    const float* Wih1      = (const float*)d_in[24];
    const float* bih1      = (const float*)d_in[26];
    const float* bhh1      = (const float*)d_in[27];
    const float* Wo        = (const float*)d_in[28];
    const float* bo        = (const float*)d_in[29];

    float* ws  = (float*)d_ws;
    float* XT0  = ws;                  // 1088*64
    float* PART = ws + 69632;          // 4*6144*64
    float* XT1  = ws + 1642496;        // 2048*64
    float* HID  = ws + 1773568;        // 64*1024 (n-major)
    float* SP   = ws + 1839104;        // 64*512  (n-major)
    float* FPART= ws + 69632;          // 20*64*160, aliases PART (dead after last lstm_act)

    float* out     = (float*)d_out;   // 64*2*80
    float* out_ctx = out + 10240;     // 64*512
    float* out_dec = out + 43008;     // 64*2560

    hidden_kernel<<<dim3(64,4), 256, 0, stream>>>(input_dec, spkr, pre_W1, pre_b1, HID);
    sp_kernel<<<dim3(64,2), 256, 0, stream>>>(speed, sp_W1, sp_b1, sp_W2, sp_b2, SP);
    p_kernel<<<dim3(64,2), 256, 0, stream>>>(HID, pre_W2, pre_b2, XT0);
    attn_kernel<<<64, 256, 0, stream>>>(input_enc, spkr, speed, lengths, We, be, Ws, conv_w,
                                        w_proj, b_proj, W_speed, SP, XT0, out_ctx, out_dec);
    gemm_tile<1088><<<dim3(96,4), 256, 0, stream>>>(XT0, Wih0, PART);
    lstm_act_kernel<<<512, 256, 0, stream>>>(PART, bih0, bhh0, XT1, nullptr);
    gemm_tile<2048><<<dim3(96,4), 256, 0, stream>>>(XT1, Wih1, PART);
    lstm_act_kernel<<<512, 256, 0, stream>>>(PART, bih1, bhh1, XT1, out_dec);
    final_partial_kernel<<<dim3(64,20), 256, 0, stream>>>(XT1, out_ctx, Wo, FPART);
    final_reduce_kernel<<<40, 256, 0, stream>>>(FPART, bo, out);
}

// Round 3
// 667.828 us; speedup vs baseline: 1.4530x; 1.0011x over previous
//
#include <hip/hip_runtime.h>
#include <math.h>

// N=64, T=2048, E=512, A=256, D=512, S=64, O=80, H4=2048
// Algebraic facts exploited:
//  - att0 one-hot at t=0 -> attention window = t in [0,10); softmax max-shift cancels
//  - h=c=0 into both LSTM cells -> Whh* unused; f-gate rows of Wih* unused
//  - conv(one-hot) = conv_w[a, 15-t]
//
// LSTM GEMM structure (gemm_bx): lane = n (64 lanes), x-chunk in 64 VGPRs,
// W staged to LDS and read via wave-uniform ds_read_b128 (broadcast, ~0 LDS BW),
// every VALU slot a v_fmac. K split 8 ways -> 768 blocks = 3/CU exactly.
//
// ws layout (floats):
//   XT0  @ 0       : 1088*64   in_lstm^T (rows 0..512 prenet p | 512..1024 ctx | 1024..1088 spkr)
//   PART @ 69632   : 8*6144*64 gemm K-split partials (i|g|o compact), reused both layers
//                    -> dead after last lstm_act; first 204800 floats reused as FPART
//   XT1  @ 3215360 : 2048*64   h1^T then h2^T
//   HID  @ 3346432 : 64*1024   prenet hidden, n-major
//   SP   @ 3411968 : 64*512    sp, n-major

__device__ __forceinline__ float sigmoidf_(float x){ return 1.0f/(1.0f+expf(-x)); }
__device__ __forceinline__ float softsignf_(float x){ return x/(1.0f+fabsf(x)); }

// async global->LDS, 16B per lane (dest = wave-uniform base + lane*16)
__device__ __forceinline__ void llds16(const float* g, float* l)
{
    __builtin_amdgcn_global_load_lds(
        (const __attribute__((address_space(1))) unsigned int*)g,
        (__attribute__((address_space(3))) unsigned int*)l, 16, 0, 0);
}

// ---- Pattern A small GEMMs: block = one n (x loads scalar-uniform), threads = j (W coalesced)

// hidden[n,j] = relu(concat(input_dec,spkr)[n,:] @ pre_W1 + pre_b1), J=1024, K=144
__global__ void hidden_kernel(const float* __restrict__ input_dec, const float* __restrict__ spkr,
                              const float* __restrict__ W, const float* __restrict__ b,
                              float* __restrict__ hid)
{
    const int n = blockIdx.x;
    const int j = blockIdx.y * 256 + threadIdx.x;   // < 1024
    float a0=0.f, a1=0.f, a2=0.f, a3=0.f;
    #pragma unroll 4
    for (int k = 0; k < 144; k += 4) {
        const float x0 = (k+0 < 80) ? input_dec[n*80 + k+0] : spkr[n*64 + (k+0-80)];
        const float x1 = (k+1 < 80) ? input_dec[n*80 + k+1] : spkr[n*64 + (k+1-80)];
        const float x2 = (k+2 < 80) ? input_dec[n*80 + k+2] : spkr[n*64 + (k+2-80)];
        const float x3 = (k+3 < 80) ? input_dec[n*80 + k+3] : spkr[n*64 + (k+3-80)];
        a0 = fmaf(x0, W[(k+0)*1024 + j], a0);
        a1 = fmaf(x1, W[(k+1)*1024 + j], a1);
        a2 = fmaf(x2, W[(k+2)*1024 + j], a2);
        a3 = fmaf(x3, W[(k+3)*1024 + j], a3);
    }
    hid[n*1024 + j] = fmaxf((a0+a1)+(a2+a3) + b[j], 0.f);
}

// sp[n,j] = tanh(relu(speed*sp_W1+sp_b1) @ sp_W2 + sp_b2), J=512, K=512
__global__ void sp_kernel(const float* __restrict__ speed, const float* __restrict__ sp_W1,
                          const float* __restrict__ sp_b1, const float* __restrict__ sp_W2,
                          const float* __restrict__ sp_b2, float* __restrict__ sp)
{
    const int n = blockIdx.x;
    const int j = blockIdx.y * 256 + threadIdx.x;   // < 512
    const float s = speed[n];
    float a0=0.f, a1=0.f, a2=0.f, a3=0.f;
    #pragma unroll 4
    for (int d = 0; d < 512; d += 4) {
        const float r0 = fmaxf(fmaf(s, sp_W1[d+0], sp_b1[d+0]), 0.f);
        const float r1 = fmaxf(fmaf(s, sp_W1[d+1], sp_b1[d+1]), 0.f);
        const float r2 = fmaxf(fmaf(s, sp_W1[d+2], sp_b1[d+2]), 0.f);
        const float r3 = fmaxf(fmaf(s, sp_W1[d+3], sp_b1[d+3]), 0.f);
        a0 = fmaf(r0, sp_W2[(d+0)*512 + j], a0);
        a1 = fmaf(r1, sp_W2[(d+1)*512 + j], a1);
        a2 = fmaf(r2, sp_W2[(d+2)*512 + j], a2);
        a3 = fmaf(r3, sp_W2[(d+3)*512 + j], a3);
    }
    sp[n*512 + j] = tanhf((a0+a1)+(a2+a3) + sp_b2[j]);
}

// p[n,j] = relu(hid[n,:] @ pre_W2 + pre_b2) -> XT0 rows [0,512), J=512, K=1024
__global__ void p_kernel(const float* __restrict__ hid, const float* __restrict__ W,
                         const float* __restrict__ b, float* __restrict__ xT0)
{
    const int n = blockIdx.x;
    const int j = blockIdx.y * 256 + threadIdx.x;   // < 512
    const float* xr = hid + n*1024;
    float a0=0.f, a1=0.f, a2=0.f, a3=0.f;
    #pragma unroll 4
    for (int k = 0; k < 1024; k += 4) {
        a0 = fmaf(xr[k+0], W[(k+0)*512 + j], a0);
        a1 = fmaf(xr[k+1], W[(k+1)*512 + j], a1);
        a2 = fmaf(xr[k+2], W[(k+2)*512 + j], a2);
        a3 = fmaf(xr[k+3], W[(k+3)*512 + j], a3);
    }
    xT0[j*64 + n] = fmaxf((a0+a1)+(a2+a3) + b[j], 0.f);
}

// attention + context, one block per batch row n, 256 threads (= a index)
__global__ void attn_kernel(const float* __restrict__ input_enc,
                            const float* __restrict__ spkr,
                            const float* __restrict__ speed,
                            const int*   __restrict__ lengths,
                            const float* __restrict__ We,
                            const float* __restrict__ be,
                            const float* __restrict__ Ws,
                            const float* __restrict__ conv_w,
                            const float* __restrict__ w_proj,
                            const float* __restrict__ b_proj,
                            const float* __restrict__ W_speed,
                            const float* __restrict__ sp,
                            float* __restrict__ xT0,
                            float* __restrict__ out_ctx,
                            float* __restrict__ out_dec)
{
    const int n = blockIdx.x;
    const int a = threadIdx.x;               // 256 threads
    __shared__ float encs[10*512];           // 20 KB
    __shared__ float part[4][10];
    __shared__ float logit_s[10];
    __shared__ float att_s[10];

    const int L1 = lengths[n] - 1;
    const int tc = (L1 + 1 < 10) ? (L1 + 1) : 10;
    const float sn = speed[n];
    const float* enc_n = input_enc + (size_t)n * (2048*512);

    for (int idx = a; idx < 10*512; idx += 256) encs[idx] = enc_n[idx];
    __syncthreads();

    float ds = 0.f;
    for (int s = 0; s < 64; ++s) ds = fmaf(spkr[n*64 + s], Ws[s*256 + a], ds);
    const float bspkr = softsignf_(ds);
    const float bspd  = sn * W_speed[a];
    const float bea   = be[a];
    const float wpa   = w_proj[a];

    float dt[10];
    #pragma unroll
    for (int t = 0; t < 10; ++t) dt[t] = 0.f;
    for (int k = 0; k < 512; ++k) {
        const float w = We[k*256 + a];
        #pragma unroll
        for (int t = 0; t < 10; ++t) dt[t] = fmaf(encs[t*512 + k], w, dt[t]);
    }

    for (int t = 0; t < 10; ++t) {
        float e = softsignf_(dt[t] + bea);
        e += bspkr + conv_w[a*31 + (15 - t)] + bspd;
        float v = tanhf(e) * wpa;
        #pragma unroll
        for (int off = 32; off > 0; off >>= 1) v += __shfl_down(v, off);
        if ((a & 63) == 0) part[a >> 6][t] = v;
    }
    __syncthreads();
    if (a < 10) logit_s[a] = part[0][a] + part[1][a] + part[2][a] + part[3][a] + b_proj[0];
    __syncthreads();
    if (a == 0) {
        float mx = -1e30f;
        for (int t = 0; t < tc; ++t) mx = fmaxf(mx, logit_s[t]);
        float ssum = 0.f;
        for (int t = 0; t < tc; ++t) { att_s[t] = expf(logit_s[t] - mx); ssum += att_s[t]; }
        const float inv = 1.f / fmaxf(ssum, 1e-12f);
        for (int t = 0; t < tc; ++t) att_s[t] *= inv;
        for (int t = tc; t < 10; ++t) att_s[t] = 0.f;
    }
    __syncthreads();

    for (int e0 = a; e0 < 512; e0 += 256) {
        const float spv = sp[n*512 + e0];
        float c = 0.f;
        for (int t = 0; t < tc; ++t) c = fmaf(att_s[t], encs[t*512 + e0] + spv, c);
        xT0[(512 + e0)*64 + n] = c;
        out_ctx[n*512 + e0]   = c;
        out_dec[n*2560 + 2048 + e0] = c;
    }
    if (a < 64) xT0[(1024 + a)*64 + n] = spkr[n*64 + a];
}

// ---- LSTM GEMM, broadcast-W structure.
// lane = n; each wave owns 16 compact j-rows; x-chunk (64 k) in VGPRs;
// W chunk (64 rows x 64 k, 16 KB) staged via global_load_lds, double-buffered;
// W read as wave-uniform float4 from LDS (broadcast). Rows processed in pairs
// (2 independent fmac chains saturate the 2-cy VALU issue). K split S ways.
template<int K, int S>
__global__ __launch_bounds__(256, 3)
void gemm_bx(const float* __restrict__ xT, const float* __restrict__ W,
             float* __restrict__ part)
{
    __shared__ __align__(16) float Wl0[64*64];   // 16 KB
    __shared__ __align__(16) float Wl1[64*64];   // 16 KB
    const int tid  = threadIdx.x;
    const int lane = tid & 63;
    const int wv   = tid >> 6;            // wave 0..3
    const int jjbase = blockIdx.x * 64;   // compact row base
    const int sy     = blockIdx.y;        // K segment
    const int jg     = jjbase + ((jjbase >= 2048) ? 2048 : 0);  // skip f-gate rows

    constexpr int NT  = K / 64;
    constexpr int NTQ = NT / S, NTR = NT % S;
    const int tn = NTQ + (sy < NTR ? 1 : 0);
    const int t0 = sy * NTQ + (sy < NTR ? sy : NTR);

    float acc[16];
    #pragma unroll
    for (int i = 0; i < 16; ++i) acc[i] = 0.f;

    auto stage = [&](int t, float* Wl) {
        const int k0 = t * 64;
        #pragma unroll
        for (int c = 0; c < 4; ++c) {
            const int r0 = (wv * 4 + c) * 4;                 // 4 rows per instr
            llds16(W + (size_t)(jg + r0 + (lane >> 4)) * K + k0 + (lane & 15) * 4,
                   Wl + r0 * 64);
        }
    };

    float xv[64];

    stage(t0, Wl0);
    {
        const int k0 = t0 * 64;
        #pragma unroll
        for (int i = 0; i < 64; ++i) xv[i] = xT[(size_t)(k0 + i) * 64 + lane];
    }
    __syncthreads();

    const float* Wc = Wl0;
    float* Wn = Wl1;
    for (int tt = 0; tt < tn; ++tt) {
        if (tt > 0) {                         // x for this chunk (xv free after prev compute)
            const int k0 = (t0 + tt) * 64;
            #pragma unroll
            for (int i = 0; i < 64; ++i) xv[i] = xT[(size_t)(k0 + i) * 64 + lane];
        }
        if (tt + 1 < tn) stage(t0 + tt + 1, Wn);   // prefetch next W behind x loads

        #pragma unroll
        for (int jp = 0; jp < 16; jp += 2) {
            const float* W0 = Wc + (wv * 16 + jp) * 64;
            const float* W1 = W0 + 64;
            float aA = 0.f, aB = 0.f;
            #pragma unroll
            for (int kk = 0; kk < 64; kk += 4) {
                const float4 wa = *(const float4*)(W0 + kk);
                const float4 wb = *(const float4*)(W1 + kk);
                aA = fmaf(wa.x, xv[kk+0], aA);  aB = fmaf(wb.x, xv[kk+0], aB);
                aA = fmaf(wa.y, xv[kk+1], aA);  aB = fmaf(wb.y, xv[kk+1], aB);
                aA = fmaf(wa.z, xv[kk+2], aA);  aB = fmaf(wb.z, xv[kk+2], aB);
                aA = fmaf(wa.w, xv[kk+3], aA);  aB = fmaf(wb.w, xv[kk+3], aB);
            }
            acc[jp]   += aA;
            acc[jp+1] += aB;
        }
        __syncthreads();
        float* t_ = (float*)Wc; Wc = Wn; Wn = t_;
    }

    float* op = part + (size_t)(sy * 6144 + jjbase + wv * 16) * 64 + lane;
    #pragma unroll
    for (int jj = 0; jj < 16; ++jj) op[jj * 64] = acc[jj];
}

// h = sigmoid(o)*tanh(sigmoid(i)*tanh(g)); fuses the 8-way K-split reduce + biases.
// Compact gate rows: i=m, g=2048+m, o=4096+m; global bias rows: i=m, g=4096+m, o=6144+m.
__global__ void lstm_act_kernel(const float* __restrict__ part,
                                const float* __restrict__ b1, const float* __restrict__ b2,
                                float* __restrict__ hT, float* __restrict__ dec_out)
{
    const int idx = blockIdx.x * 256 + threadIdx.x;   // 64*2048
    const int n = idx & 63;
    const int m = idx >> 6;
    float gi = b1[m]        + b2[m];
    float gg = b1[4096 + m] + b2[4096 + m];
    float go = b1[6144 + m] + b2[6144 + m];
    #pragma unroll
    for (int s = 0; s < 8; ++s) {
        gi += part[(size_t)(s * 6144 +        m) * 64 + n];
        gg += part[(size_t)(s * 6144 + 2048 + m) * 64 + n];
        go += part[(size_t)(s * 6144 + 4096 + m) * 64 + n];
    }
    const float c = sigmoidf_(gi) * tanhf(gg);
    const float h = sigmoidf_(go) * tanhf(c);
    hT[idx] = h;
    if (dec_out) dec_out[n*2560 + m] = h;
}

// final GEMM, K-split: out[n,j] = dec_output[n,:] @ Wo + bo
__global__ void final_partial_kernel(const float* __restrict__ h2T, const float* __restrict__ ctx,
                                     const float* __restrict__ Wo, float* __restrict__ part)
{
    const int n  = blockIdx.x;
    const int kc = blockIdx.y;
    const int j  = threadIdx.x;               // 160 active
    if (j >= 160) return;
    const int k0 = kc * 128;
    float a0=0.f, a1=0.f, a2=0.f, a3=0.f;
    if (kc < 16) {
        #pragma unroll 4
        for (int k = k0; k < k0 + 128; k += 4) {
            a0 = fmaf(h2T[(k+0)*64 + n], Wo[(k+0)*160 + j], a0);
            a1 = fmaf(h2T[(k+1)*64 + n], Wo[(k+1)*160 + j], a1);
            a2 = fmaf(h2T[(k+2)*64 + n], Wo[(k+2)*160 + j], a2);
            a3 = fmaf(h2T[(k+3)*64 + n], Wo[(k+3)*160 + j], a3);
        }
    } else {
        const float* cr = ctx + n*512;
        #pragma unroll 4
        for (int k = k0; k < k0 + 128; k += 4) {
            a0 = fmaf(cr[k+0-2048], Wo[(k+0)*160 + j], a0);
            a1 = fmaf(cr[k+1-2048], Wo[(k+1)*160 + j], a1);
            a2 = fmaf(cr[k+2-2048], Wo[(k+2)*160 + j], a2);
            a3 = fmaf(cr[k+3-2048], Wo[(k+3)*160 + j], a3);
        }
    }
    part[(kc*64 + n)*160 + j] = (a0+a1)+(a2+a3);
}

__global__ void final_reduce_kernel(const float* __restrict__ part, const float* __restrict__ bo,
                                    float* __restrict__ out)
{
    const int idx = blockIdx.x * 256 + threadIdx.x;   // < 10240 = 64*160
    const int j = idx - (idx / 160) * 160;
    float s = bo[j];
    #pragma unroll
    for (int kc = 0; kc < 20; ++kc) s += part[kc*10240 + idx];
    out[idx] = s;
}

extern "C" void kernel_launch(void* const* d_in, const int* in_sizes, int n_in,
                              void* d_out, int out_size, void* d_ws, size_t ws_size,
                              hipStream_t stream)
{
    const float* input_enc = (const float*)d_in[0];
    const float* input_dec = (const float*)d_in[1];
    const float* spkr      = (const float*)d_in[2];
    const float* speed     = (const float*)d_in[3];
    const int*   lengths   = (const int*)  d_in[4];
    const float* We        = (const float*)d_in[5];
    const float* be        = (const float*)d_in[6];
    const float* Ws        = (const float*)d_in[7];
    const float* conv_w    = (const float*)d_in[8];
    const float* w_proj    = (const float*)d_in[9];
    const float* b_proj    = (const float*)d_in[10];
    const float* W_speed   = (const float*)d_in[11];
    const float* sp_W1     = (const float*)d_in[12];
    const float* sp_b1     = (const float*)d_in[13];
    const float* sp_W2     = (const float*)d_in[14];
    const float* sp_b2     = (const float*)d_in[15];
    const float* pre_W1    = (const float*)d_in[16];
    const float* pre_b1    = (const float*)d_in[17];
    const float* pre_W2    = (const float*)d_in[18];
    const float* pre_b2    = (const float*)d_in[19];
    const float* Wih0      = (const float*)d_in[20];
    const float* bih0      = (const float*)d_in[22];
    const float* bhh0      = (const float*)d_in[23];
    const float* Wih1      = (const float*)d_in[24];
    const float* bih1      = (const float*)d_in[26];
    const float* bhh1      = (const float*)d_in[27];
    const float* Wo        = (const float*)d_in[28];
    const float* bo        = (const float*)d_in[29];

    float* ws   = (float*)d_ws;
    float* XT0  = ws;                  // 1088*64
    float* PART = ws + 69632;          // 8*6144*64
    float* XT1  = ws + 3215360;        // 2048*64
    float* HID  = ws + 3346432;        // 64*1024 (n-major)
    float* SP   = ws + 3411968;        // 64*512  (n-major)
    float* FPART= ws + 69632;          // 20*64*160, aliases PART (dead after last lstm_act)

    float* out     = (float*)d_out;   // 64*2*80
    float* out_ctx = out + 10240;     // 64*512
    float* out_dec = out + 43008;     // 64*2560

    hidden_kernel<<<dim3(64,4), 256, 0, stream>>>(input_dec, spkr, pre_W1, pre_b1, HID);
    sp_kernel<<<dim3(64,2), 256, 0, stream>>>(speed, sp_W1, sp_b1, sp_W2, sp_b2, SP);
    p_kernel<<<dim3(64,2), 256, 0, stream>>>(HID, pre_W2, pre_b2, XT0);
    attn_kernel<<<64, 256, 0, stream>>>(input_enc, spkr, speed, lengths, We, be, Ws, conv_w,
                                        w_proj, b_proj, W_speed, SP, XT0, out_ctx, out_dec);
    gemm_bx<1088, 8><<<dim3(96,8), 256, 0, stream>>>(XT0, Wih0, PART);
    lstm_act_kernel<<<512, 256, 0, stream>>>(PART, bih0, bhh0, XT1, nullptr);
    gemm_bx<2048, 8><<<dim3(96,8), 256, 0, stream>>>(XT1, Wih1, PART);
    lstm_act_kernel<<<512, 256, 0, stream>>>(PART, bih1, bhh1, XT1, out_dec);
    final_partial_kernel<<<dim3(64,20), 256, 0, stream>>>(XT1, out_ctx, Wo, FPART);
    final_reduce_kernel<<<40, 256, 0, stream>>>(FPART, bo, out);
}